// Round 10
// baseline (823.857 us; speedup 1.0000x reference)
//
#include <hip/hip_runtime.h>
#include <hip/hip_bf16.h>

// out[b,e] = m[c,e] + sum_d z[b,d] * L[c,e,d],  c = components[b]
// v10 = v9 pipeline + split-K=4 (2560 blocks) + IN-KERNEL flag reduction.
// Evidence: the only config that beat ~89us gmm was v3's 2560-block split-K
// (~65us) -> the binding constraint is issuing-wave count per CU (load
// concurrency), not schedule depth (v7-v9 all neutral). Split-K returns at
// 4x block count; the v3-killing reduce kernel + extra launches are replaced
// by a last-arriver in-kernel merge: store partials, __threadfence (agent
// fence -> L2 writeback), agent-scope atomicAdd on a per-(k,ntile) flag;
// the 4th block re-reads the 3 partials via agent-scope atomic loads
// (coherence-point reads; safe under non-coherent per-XCD L2; no spinning ->
// no co-residency assumption). Flags zeroed in build_map (kernel-boundary
// flush, same mechanism that makes zb visible - proven v6-v9).

#define DDIM  2048
#define BSAMP 1024
#define KCOMP 10
#define MPAD  160                      // max n_k pad; Binom(1024,0.1)+6sigma
#define NT    32                       // block N tile
#define BK    32                       // d-elems per iteration
#define NITER (DDIM / BK)              // 64 total d-tiles
#define SPLITS 4
#define NS    (NITER / SPLITS)         // 16 d-tiles per block
#define TILEP 12288                    // padded zb tile stride
#define BBYTES 4096                    // fp32 B stage bytes
#define NBUF  3                        // 12 KB LDS total
#define NXCD  8
#define NWG   (KCOMP * 64 * SPLITS)    // 2560; %8==0 -> bijective swizzle
#define PSZ   (MPAD * NT)              // 5120 floats per partial slice

typedef __attribute__((ext_vector_type(8))) short bf16x8;  // 8 bf16 = 4 VGPRs
typedef __attribute__((ext_vector_type(4))) float f32x4;

__device__ __forceinline__ void async16(void* lds, const void* g) {
    __builtin_amdgcn_global_load_lds(
        (const __attribute__((address_space(1))) void*)g,
        (__attribute__((address_space(3))) void*)lds, 16, 0, 0);
}

__device__ __forceinline__ short bfs(float x) {
    __hip_bfloat16 h = __float2bfloat16(x);   // RNE
    return *reinterpret_cast<short*>(&h);
}

// pinned-order 16B global load (counts exactly 1 vmcnt op)
__device__ __forceinline__ bf16x8 gld16(const void* p) {
    bf16x8 r;
    asm volatile("global_load_dwordx4 %0, %1, off" : "=v"(r) : "v"(p));
    return r;
}

// Kernel 1: counting-bucket (proven v1-v9) + zero the 640 group flags.
__global__ void build_map(const int* __restrict__ comp,
                          int* __restrict__ rowmap,
                          int* __restrict__ counts,
                          int* __restrict__ flags) {
    __shared__ int sc[KCOMP];
    const int t = threadIdx.x;
    if (t < KCOMP) sc[t] = 0;
    if (t < KCOMP * 64) flags[t] = 0;          // visible to gmm via kernel
    __syncthreads();                           // boundary flush (as zb is)
    const int c = comp[t];
    const int r = atomicAdd(&sc[c], 1);
    if (r < MPAD) rowmap[c * MPAD + r] = t;
    __syncthreads();
    if (t < KCOMP) counts[t] = sc[t];
}

// Kernel 2: build the tiled zb image (proven v6-v9, unchanged).
__global__ void zgather(const float* __restrict__ z,
                        const int* __restrict__ rowmap,
                        short* __restrict__ zb) {
    const int k  = blockIdx.x;
    const int sp = blockIdx.y;                  // slot pair / macro-row
    const int t  = threadIdx.x;
    const int c  = t & 7;                       // chunk within macro-row
    const int g  = c & 3;
    const int s0 = rowmap[k * MPAD + 2 * sp]     & (BSAMP - 1);
    const int s1 = rowmap[k * MPAD + 2 * sp + 1] & (BSAMP - 1);
    const int src = (c >> 2) ? s1 : s0;
    const int swz = (c ^ (sp & 7)) * 16;        // byte offset within 128B
    char* kbase = (char*)zb + (size_t)k * NITER * TILEP + sp * 128 + swz;
#pragma unroll
    for (int p = 0; p < 2; ++p) {
        const int it = p * 32 + (t >> 3);
        const float* zr = z + (size_t)src * DDIM + it * BK + g * 8;
        f32x4 x = *(const f32x4*)zr;
        f32x4 y = *(const f32x4*)(zr + 4);
        bf16x8 r;
#pragma unroll
        for (int i = 0; i < 4; ++i) { r[i] = bfs(x[i]); r[4 + i] = bfs(y[i]); }
        *(bf16x8*)(kbase + (size_t)it * TILEP) = r;
    }
}

// Kernel 3: grid = 2560 (1D, XCD-swizzled), block = 256 (4 waves).
// newlin = k*256 + nt*4 + s (s = d-split). XCD chunk of 320 consecutive
// newlin keeps split-groups together + <=2 k's of A-tiles in local L2.
// Block computes d-range [s*16, s*16+16) tiles; v9 pipeline with NS=16:
// waits 12/6 steady; peel 12/6, 12/6, 11/6, 5/0 (ledger re-verified).
__global__ __launch_bounds__(256, 4)
void gmm_gemm(const short* __restrict__ zb,
              const float* __restrict__ mvec,
              const float* __restrict__ Lmat,
              const int* __restrict__ rowmap,
              const int* __restrict__ counts,
              float* __restrict__ out,
              float* __restrict__ partials,
              int* __restrict__ flags) {
    __shared__ __attribute__((aligned(16))) char smem[NBUF * BBYTES];
    __shared__ int s_old;
    const int t    = threadIdx.x;
    const int lane = t & 63;
    const int w    = t >> 6;
    const int mh   = w >> 1;          // wave M-half (80 rows)
    const int nh   = w & 1;           // wave N-half (16 cols)
    const int lin  = blockIdx.x;
    const int newlin = (lin & (NXCD - 1)) * (NWG / NXCD) + (lin >> 3);
    const int s    = newlin & 3;                 // d-split
    const int nt   = (newlin >> 2) & 63;         // n-tile
    const int k    = newlin >> 8;                // component
    const int n0   = nt * NT;
    const int tb   = s * NS;                     // global d-tile base
    const int group = newlin >> 2;               // k*64 + nt
    const float* Lk = Lmat + (size_t)k * DDIM * DDIM;
    const char* zt  = (const char*)zb + (size_t)k * NITER * TILEP;
    const int cnt  = counts[k];

    int mtmax = (cnt - mh * 80 + 15) >> 4;
    mtmax = mtmax < 0 ? 0 : (mtmax > 5 ? 5 : mtmax);

    // B staging: 256 chunks (row = t>>3, h = t&7), pre-swizzled source col
    const int br = t >> 3,          bc = ((t & 7) ^ (br & 7)) * 4;
    const unsigned ub = (unsigned)(t & ~63) * 16;   // wave-uniform byte base

    const int fr = lane & 15;        // frag row
    const int g  = lane >> 4;        // k-group (8 elems) of this lane
    const int rb = nh * 16 + fr;     // B row (block-relative e)
    const int h0 = ((2 * g)     ^ (rb & 7)) * 4;
    const int h1 = ((2 * g + 1) ^ (rb & 7)) * 4;
    const int frh = fr >> 1;
    const int fra = (fr & 1) * 4 + g;
    const char* za = zt + mh * 5120 + frh * 128 + ((fra ^ frh) * 16);

    f32x4 acc[5];
#pragma unroll
    for (int mt = 0; mt < 5; ++mt) acc[mt] = (f32x4){0.f, 0.f, 0.f, 0.f};

    bf16x8 a0[5], a1[5];

    auto stageB = [&](int bi, int it) {             // exactly 1 vm op
        async16(smem + bi * BBYTES + ub,
                Lk + (size_t)(n0 + br) * DDIM + (tb + it) * BK + bc);
    };
    auto loadA = [&](bf16x8 (&a)[5], int it) {      // exactly 5 vm ops
        const char* p = za + (size_t)(tb + it) * TILEP;
#pragma unroll
        for (int mt = 0; mt < 5; ++mt) a[mt] = gld16(p + mt * 1024);
    };
    auto computeB = [&](int bi) {
        const float* B = (const float*)(smem + bi * BBYTES);
        f32x4 x = *(const f32x4*)(B + rb * 32 + h0);
        f32x4 y = *(const f32x4*)(B + rb * 32 + h1);
        bf16x8 bb;
#pragma unroll
        for (int i = 0; i < 4; ++i) { bb[i] = bfs(x[i]); bb[4 + i] = bfs(y[i]); }
        return bb;
    };
    auto mfma5 = [&](bf16x8 (&a)[5], bf16x8 bb) {
#pragma unroll
        for (int mt = 0; mt < 5; ++mt)
            if (mt < mtmax)
                acc[mt] = __builtin_amdgcn_mfma_f32_16x16x32_bf16(a[mt], bb, acc[mt], 0, 0, 0);
    };

    // prologue
    stageB(0, 0); loadA(a0, 0); stageB(1, 1); loadA(a1, 1); stageB(2, 2);

    int bi = 0;
    for (int j = 0; j < NS - 4; j += 2) {           // j < 12
        asm volatile("s_waitcnt vmcnt(12)" ::: "memory");
        __builtin_amdgcn_s_barrier();
        {
            bf16x8 bb = computeB(bi);
            asm volatile("s_waitcnt vmcnt(6)" ::: "memory");
            __builtin_amdgcn_sched_barrier(0);
            mfma5(a0, bb);
        }
        loadA(a0, j + 2);
        __builtin_amdgcn_s_barrier();
        stageB(bi, j + 3);
        bi = (bi == NBUF - 1) ? 0 : bi + 1;

        asm volatile("s_waitcnt vmcnt(12)" ::: "memory");
        __builtin_amdgcn_s_barrier();
        {
            bf16x8 bb = computeB(bi);
            asm volatile("s_waitcnt vmcnt(6)" ::: "memory");
            __builtin_amdgcn_sched_barrier(0);
            mfma5(a1, bb);
        }
        loadA(a1, j + 3);
        __builtin_amdgcn_s_barrier();
        stageB(bi, j + 4);
        bi = (bi == NBUF - 1) ? 0 : bi + 1;
    }
    // phase NS-4 = 12 (a0): loads A14, stages B15
    asm volatile("s_waitcnt vmcnt(12)" ::: "memory");
    __builtin_amdgcn_s_barrier();
    {
        bf16x8 bb = computeB(bi);
        asm volatile("s_waitcnt vmcnt(6)" ::: "memory");
        __builtin_amdgcn_sched_barrier(0);
        mfma5(a0, bb);
    }
    loadA(a0, NS - 2);
    __builtin_amdgcn_s_barrier();
    stageB(bi, NS - 1);
    bi = (bi == NBUF - 1) ? 0 : bi + 1;
    // phase 13 (a1): loads A15, no stage
    asm volatile("s_waitcnt vmcnt(12)" ::: "memory");
    __builtin_amdgcn_s_barrier();
    {
        bf16x8 bb = computeB(bi);
        asm volatile("s_waitcnt vmcnt(6)" ::: "memory");
        __builtin_amdgcn_sched_barrier(0);
        mfma5(a1, bb);
    }
    loadA(a1, NS - 1);
    __builtin_amdgcn_s_barrier();
    bi = (bi == NBUF - 1) ? 0 : bi + 1;
    // phase 14 (a0): no load/stage
    asm volatile("s_waitcnt vmcnt(11)" ::: "memory");
    __builtin_amdgcn_s_barrier();
    {
        bf16x8 bb = computeB(bi);
        asm volatile("s_waitcnt vmcnt(6)" ::: "memory");
        __builtin_amdgcn_sched_barrier(0);
        mfma5(a0, bb);
    }
    __builtin_amdgcn_s_barrier();
    bi = (bi == NBUF - 1) ? 0 : bi + 1;
    // phase 15 (a1): drain
    asm volatile("s_waitcnt vmcnt(5)" ::: "memory");
    __builtin_amdgcn_s_barrier();
    {
        bf16x8 bb = computeB(bi);
        asm volatile("s_waitcnt vmcnt(0)" ::: "memory");
        __builtin_amdgcn_sched_barrier(0);
        mfma5(a1, bb);
    }

    // ---- split-K merge ----
    // C/D layout col=lane&15, row=(lane>>4)*4+reg (m89-verified)
    const int rquad = g * 4;
    const int lcol  = nh * 16 + fr;
    const int e     = n0 + lcol;
    float* Pg = partials + (size_t)group * (SPLITS * PSZ);
    float* Ps = Pg + s * PSZ;
#pragma unroll
    for (int mt = 0; mt < 5; ++mt) {
        if (mt < mtmax) {
            const int sb = mh * 80 + mt * 16 + rquad;
#pragma unroll
            for (int r = 0; r < 4; ++r)
                Ps[(sb + r) * NT + lcol] = acc[mt][r];
        }
    }
    __threadfence();                              // agent fence: L2 writeback
    if (t == 0)
        s_old = __hip_atomic_fetch_add(&flags[group], 1, __ATOMIC_ACQ_REL,
                                       __HIP_MEMORY_SCOPE_AGENT);
    __syncthreads();
    if (s_old == SPLITS - 1) {                    // last arriver merges
        const float mu = mvec[k * DDIM + e];
#pragma unroll
        for (int mt = 0; mt < 5; ++mt) {
            if (mt < mtmax) {
                const int sb = mh * 80 + mt * 16 + rquad;
#pragma unroll
                for (int r = 0; r < 4; ++r) {
                    const int slot = sb + r;
                    if (slot < cnt) {
                        float sum = acc[mt][r];
#pragma unroll
                        for (int q = 1; q < SPLITS; ++q) {
                            float* pp = Pg + ((s + q) & 3) * PSZ + slot * NT + lcol;
                            sum += __hip_atomic_load(pp, __ATOMIC_RELAXED,
                                                     __HIP_MEMORY_SCOPE_AGENT);
                        }
                        const int b = rowmap[k * MPAD + slot];
                        out[(size_t)b * DDIM + e] = sum + mu;
                    }
                }
            }
        }
    }
}

extern "C" void kernel_launch(void* const* d_in, const int* in_sizes, int n_in,
                              void* d_out, int out_size, void* d_ws, size_t ws_size,
                              hipStream_t stream) {
    const float* z    = (const float*)d_in[0];
    const float* mvec = (const float*)d_in[1];
    const float* Lmat = (const float*)d_in[2];
    const int* comp   = (const int*)d_in[3];
    float* out        = (float*)d_out;

    int* rowmap = (int*)d_ws;                         // K*MPAD ints = 6400 B
    int* counts = rowmap + KCOMP * MPAD;              // K ints
    const size_t zb_off = 8192;
    const size_t zb_bytes = (size_t)KCOMP * NITER * TILEP;          // 7.87 MB
    const size_t pt_off = zb_off + zb_bytes;
    const size_t pt_bytes = (size_t)KCOMP * 64 * SPLITS * PSZ * 4;  // 52.4 MB
    short* zb       = (short*)((char*)d_ws + zb_off);
    float* partials = (float*)((char*)d_ws + pt_off);
    int*   flags    = (int*)((char*)d_ws + pt_off + pt_bytes);

    build_map<<<1, BSAMP, 0, stream>>>(comp, rowmap, counts, flags);
    zgather<<<dim3(KCOMP, MPAD / 2), 256, 0, stream>>>(z, rowmap, zb);
    gmm_gemm<<<NWG, 256, 0, stream>>>(zb, mvec, Lmat, rowmap, counts, out,
                                      partials, flags);
}

// Round 11
// 268.382 us; speedup vs baseline: 3.0697x; 3.0697x over previous
//
#include <hip/hip_runtime.h>
#include <hip/hip_bf16.h>

// out[b,e] = m[c,e] + sum_d z[b,d] * L[c,e,d],  c = components[b]
// v11 = v7 structure with NT=128 (the byte-reduction lever).
// Evidence: v5-v9 all pinned at gmm ~88-103us across 4 different schedules;
// bytes-into-CU (A 419 + B 168 = 587 MB) / 88us = 6.7 TB/s = the same rate
// the harness fill sustains -> aggregate data-motion ceiling, not schedule.
// v10's occupancy doubling made it WORSE (merge serialization) -> wave-count
// theory dead. Only lever: move fewer bytes. NT=128 cuts A re-reads 4x:
// 105 + 168 = 290 MB -> predicted gmm ~50us.
// Tile 160x128, 512 thr (8 waves = 2mh x 4nq, wave 80x32, acc[5][2]).
// Stage: A 16KB (640 real chunks; threads 128..511 of instr-2 clamp-dup
// chunk 639 so ALL threads issue exactly 4 ops -> v7's exact vmcnt ledger
// 8/4/0 holds) + B 16KB; depth-3 ring = 96KB LDS, 1 block/CU, 160 blocks.
// build_map / zgather / frag maps / epilogue byte-identical to v6-v9.

#define DDIM  2048
#define BSAMP 1024
#define KCOMP 10
#define MPAD  160                      // max n_k pad; Binom(1024,0.1)+6sigma
#define NT    128                      // block N tile
#define BK    32                       // d-elems per iteration
#define NITER (DDIM / BK)              // 64
#define TILEP 12288                    // zb tile stride (640 real chunks)
#define ALDS  16384                    // A LDS region (1024 chunk slots)
#define STAGE_BYTES 32768              // A 16K + B 16K
#define NBUF  3                        // 96 KB LDS -> 1 block/CU

typedef __attribute__((ext_vector_type(8))) short bf16x8;  // 8 bf16 = 4 VGPRs
typedef __attribute__((ext_vector_type(4))) float f32x4;

__device__ __forceinline__ void async16(void* lds, const void* g) {
    __builtin_amdgcn_global_load_lds(
        (const __attribute__((address_space(1))) void*)g,
        (__attribute__((address_space(3))) void*)lds, 16, 0, 0);
}

__device__ __forceinline__ short bfs(float x) {
    __hip_bfloat16 h = __float2bfloat16(x);   // RNE
    return *reinterpret_cast<short*>(&h);
}

// Kernel 1: counting-bucket the 1024 samples by component (proven v1-v9).
__global__ void build_map(const int* __restrict__ comp,
                          int* __restrict__ rowmap,
                          int* __restrict__ counts) {
    __shared__ int sc[KCOMP];
    const int t = threadIdx.x;
    if (t < KCOMP) sc[t] = 0;
    __syncthreads();
    const int c = comp[t];
    const int r = atomicAdd(&sc[c], 1);
    if (r < MPAD) rowmap[c * MPAD + r] = t;
    __syncthreads();
    if (t < KCOMP) counts[t] = sc[t];
}

// Kernel 2: build the tiled zb image (proven v6-v9, unchanged).
__global__ void zgather(const float* __restrict__ z,
                        const int* __restrict__ rowmap,
                        short* __restrict__ zb) {
    const int k  = blockIdx.x;
    const int sp = blockIdx.y;                  // slot pair / macro-row
    const int t  = threadIdx.x;
    const int c  = t & 7;                       // chunk within macro-row
    const int g  = c & 3;
    const int s0 = rowmap[k * MPAD + 2 * sp]     & (BSAMP - 1);
    const int s1 = rowmap[k * MPAD + 2 * sp + 1] & (BSAMP - 1);
    const int src = (c >> 2) ? s1 : s0;
    const int swz = (c ^ (sp & 7)) * 16;        // byte offset within 128B
    char* kbase = (char*)zb + (size_t)k * NITER * TILEP + sp * 128 + swz;
#pragma unroll
    for (int p = 0; p < 2; ++p) {
        const int it = p * 32 + (t >> 3);
        const float* zr = z + (size_t)src * DDIM + it * BK + g * 8;
        f32x4 x = *(const f32x4*)zr;
        f32x4 y = *(const f32x4*)(zr + 4);
        bf16x8 r;
#pragma unroll
        for (int i = 0; i < 4; ++i) { r[i] = bfs(x[i]); r[4 + i] = bfs(y[i]); }
        *(bf16x8*)(kbase + (size_t)it * TILEP) = r;
    }
}

// Kernel 3: grid = (16, 10) = 160 blocks, block = 512 (8 waves).
// Block tile 160x128; wave tile 80x32 (mh = w&1, nq = w>>1). acc[5][2].
// Depth-3 ring, v7 ledger: steady vmcnt(8); tail vmcnt(4), vmcnt(0).
__global__ __launch_bounds__(512, 1)
void gmm_gemm(const short* __restrict__ zb,
              const float* __restrict__ mvec,
              const float* __restrict__ Lmat,
              const int* __restrict__ rowmap,
              const int* __restrict__ counts,
              float* __restrict__ out) {
    __shared__ __attribute__((aligned(16))) char smem[NBUF * STAGE_BYTES];
    const int t    = threadIdx.x;
    const int lane = t & 63;
    const int w    = t >> 6;          // 0..7
    const int mh   = w & 1;           // wave M-half (80 rows)
    const int nq   = w >> 1;          // wave N-quarter (32 cols)
    const int k    = blockIdx.y;
    const int n0   = blockIdx.x * NT;
    const float* Lk = Lmat + (size_t)k * DDIM * DDIM;
    const char* zt  = (const char*)zb + (size_t)k * NITER * TILEP;
    const int cnt  = counts[k];

    // count-aware trim: this wave's rows are mh*80 + mt*16 + {0..15}
    int mtmax = (cnt - mh * 80 + 15) >> 4;
    mtmax = mtmax < 0 ? 0 : (mtmax > 5 ? 5 : mtmax);

    // B staging: 1024 chunks (row = c>>3, h = c&7, pre-swizzled source col),
    // thread t owns chunks t and 512+t.
    const int br0 = t >> 3,        bc0 = ((t & 7) ^ (br0 & 7)) * 4;
    const int c1  = 512 + t;
    const int br1 = c1 >> 3,       bc1 = ((c1 & 7) ^ (br1 & 7)) * 4;
    // A staging: chunks t and min(512+t, 639) (clamp-dup keeps op count
    // uniform; dup lines are L1/L2 hits, LDS slots 640+ never read).
    const int ac1 = (512 + t < 640) ? (512 + t) : 639;
    const unsigned ub = (unsigned)(t & ~63) * 16;   // wave-uniform byte base

    auto stage = [&](int bi, int it) {              // exactly 4 ops/thread
        char* lb = smem + bi * STAGE_BYTES;
        const char* at = zt + (size_t)it * TILEP;
        async16(lb + ub,               at + t * 16);
        async16(lb + 8192 + ub,        at + ac1 * 16);
        async16(lb + ALDS + ub,        Lk + (size_t)(n0 + br0) * DDIM + it * BK + bc0);
        async16(lb + ALDS + 8192 + ub, Lk + (size_t)(n0 + br1) * DDIM + it * BK + bc1);
    };

    f32x4 acc[5][2];
#pragma unroll
    for (int mt = 0; mt < 5; ++mt) {
        acc[mt][0] = (f32x4){0.f, 0.f, 0.f, 0.f};
        acc[mt][1] = (f32x4){0.f, 0.f, 0.f, 0.f};
    }

    const int fr = lane & 15;        // frag row
    const int g  = lane >> 4;        // k-group (8 elems) of this lane
    const int rb0 = nq * 32 + fr;    // B rows (block-relative e)
    const int rb1 = rb0 + 16;
    const int h00 = ((2 * g)     ^ (rb0 & 7)) * 4;
    const int h01 = ((2 * g + 1) ^ (rb0 & 7)) * 4;
    const int h10 = ((2 * g)     ^ (rb1 & 7)) * 4;
    const int h11 = ((2 * g + 1) ^ (rb1 & 7)) * 4;
    const int frh = fr >> 1;
    const int fra = (fr & 1) * 4 + g;
    const int abase = (mh * 40 + frh) * 128 + ((fra ^ frh) * 16);

    auto compute = [&](int bi) {
        const char* lb = smem + bi * STAGE_BYTES;
        const float* B = (const float*)(lb + ALDS);
        f32x4 x0 = *(const f32x4*)(B + rb0 * 32 + h00);
        f32x4 y0 = *(const f32x4*)(B + rb0 * 32 + h01);
        f32x4 x1 = *(const f32x4*)(B + rb1 * 32 + h10);
        f32x4 y1 = *(const f32x4*)(B + rb1 * 32 + h11);
        bf16x8 b0, b1;
#pragma unroll
        for (int i = 0; i < 4; ++i) {
            b0[i] = bfs(x0[i]); b0[4 + i] = bfs(y0[i]);
            b1[i] = bfs(x1[i]); b1[4 + i] = bfs(y1[i]);
        }
#pragma unroll
        for (int mt = 0; mt < 5; ++mt) {
            if (mt < mtmax) {        // wave-uniform guard, static acc index
                bf16x8 a = *(const bf16x8*)(lb + abase + mt * 1024);
                acc[mt][0] = __builtin_amdgcn_mfma_f32_16x16x32_bf16(a, b0, acc[mt][0], 0, 0, 0);
                acc[mt][1] = __builtin_amdgcn_mfma_f32_16x16x32_bf16(a, b1, acc[mt][1], 0, 0, 0);
            }
        }
    };

    stage(0, 0); stage(1, 1); stage(2, 2);          // 12 ops/thread in flight
    int bi = 0;
    for (int it = 0; it < NITER - 2; ++it) {
        asm volatile("s_waitcnt vmcnt(8)" ::: "memory");  // stage(it) landed
        __builtin_amdgcn_s_barrier();                     // buf bi full
        compute(bi);
        __builtin_amdgcn_s_barrier();                     // buf bi consumed
        if (it + 3 < NITER) stage(bi, it + 3);
        bi = (bi == NBUF - 1) ? 0 : bi + 1;
    }
    // it = NITER-2: stages NITER-2, NITER-1 outstanding (8 ops)
    asm volatile("s_waitcnt vmcnt(4)" ::: "memory");
    __builtin_amdgcn_s_barrier();
    compute(bi);
    __builtin_amdgcn_s_barrier();
    bi = (bi == NBUF - 1) ? 0 : bi + 1;
    // it = NITER-1: drain all
    asm volatile("s_waitcnt vmcnt(0)" ::: "memory");
    __builtin_amdgcn_s_barrier();
    compute(bi);

    // epilogue: C/D layout col=lane&15, row=(lane>>4)*4+reg (m89-verified)
    const int rquad = g * 4;
#pragma unroll
    for (int nt16 = 0; nt16 < 2; ++nt16) {
        const int e = n0 + nq * 32 + nt16 * 16 + fr;
        const float mu = mvec[k * DDIM + e];
#pragma unroll
        for (int mt = 0; mt < 5; ++mt) {
            if (mt < mtmax) {
                const int sb = mh * 80 + mt * 16 + rquad;
#pragma unroll
                for (int r = 0; r < 4; ++r) {
                    const int slot = sb + r;
                    if (slot < cnt) {
                        const int b = rowmap[k * MPAD + slot];
                        out[(size_t)b * DDIM + e] = acc[mt][nt16][r] + mu;
                    }
                }
            }
        }
    }
}

extern "C" void kernel_launch(void* const* d_in, const int* in_sizes, int n_in,
                              void* d_out, int out_size, void* d_ws, size_t ws_size,
                              hipStream_t stream) {
    const float* z    = (const float*)d_in[0];
    const float* mvec = (const float*)d_in[1];
    const float* Lmat = (const float*)d_in[2];
    const int* comp   = (const int*)d_in[3];
    float* out        = (float*)d_out;

    int* rowmap = (int*)d_ws;                         // K*MPAD ints = 6400 B
    int* counts = rowmap + KCOMP * MPAD;              // K ints
    short* zb   = (short*)((char*)d_ws + 8192);       // 7.87 MB tiled image

    build_map<<<1, BSAMP, 0, stream>>>(comp, rowmap, counts);
    zgather<<<dim3(KCOMP, MPAD / 2), 256, 0, stream>>>(z, rowmap, zb);
    gmm_gemm<<<dim3(DDIM / NT, KCOMP), 512, 0, stream>>>(zb, mvec, Lmat,
                                                         rowmap, counts, out);
}